// Round 1
// baseline (33.980 us; speedup 1.0000x reference)
//
#include <hip/hip_runtime.h>

#define N_SEQS 2048
#define SEQ_LEN 512
#define NAA 20
#define MPOS 100

// ---------------------------------------------------------------------------
// Pack columns 0..99 of msa into contiguous uint8 [MPOS][N_SEQS] for the MI
// kernel (turns scattered stride-2048B reads into coalesced 2KB column reads).
// ---------------------------------------------------------------------------
__global__ void pack_cols_kernel(const int* __restrict__ msa,
                                 unsigned char* __restrict__ cols) {
    int i = blockIdx.x;
    for (int n = threadIdx.x; n < N_SEQS; n += blockDim.x) {
        cols[i * N_SEQS + n] = (unsigned char)msa[n * SEQ_LEN + i];
    }
}

// ---------------------------------------------------------------------------
// Per-position PSSM + conservation. One block per position.
// ---------------------------------------------------------------------------
__global__ void pssm_cons_kernel(const int* __restrict__ msa,
                                 const float* __restrict__ pc,
                                 float* __restrict__ pssm,
                                 float* __restrict__ cons) {
    __shared__ int hist[NAA];
    __shared__ float s_tot;
    const int i = blockIdx.x;
    const int tid = threadIdx.x;

    if (tid < NAA) hist[tid] = 0;
    __syncthreads();

    for (int n = tid; n < N_SEQS; n += blockDim.x) {
        int v = msa[n * SEQ_LEN + i];
        if (v < NAA) atomicAdd(&hist[v], 1);
    }
    __syncthreads();

    if (tid == 0) {
        int t = 0;
#pragma unroll
        for (int a = 0; a < NAA; ++a) t += hist[a];
        s_tot = (float)t;
    }
    __syncthreads();

    const float pcnt = 0.01f * pc[0];
    if (tid < NAA) {
        float freq = ((float)hist[tid] + pcnt) / (2048.0f + pcnt * 20.0f);
        pssm[i * NAA + tid] = logf(freq * 20.0f + 1e-10f);
    }
    if (tid == 0) {
        float tot = s_tot;
        float ts = fmaxf(tot, 1.0f);
        float e = 0.0f;
#pragma unroll
        for (int a = 0; a < NAA; ++a) {
            float f = (float)hist[a] / ts;
            e -= f * log2f(f + 1e-10f);
        }
        cons[i] = (tot > 0.0f) ? (1.0f - e / 4.321928094887363f) : 0.0f;
    }
}

// ---------------------------------------------------------------------------
// MI for one (i<j) position pair per block. 256 threads, 4 per-wave LDS
// histograms (20x20) -> merge -> marginals -> sum of p*log2 terms.
// ---------------------------------------------------------------------------
__global__ __launch_bounds__(256) void mi_kernel(const int* __restrict__ msa,
                                                 const unsigned char* __restrict__ cols,
                                                 int use_pack,
                                                 float* __restrict__ mi) {
    const int j = blockIdx.x;
    const int i = blockIdx.y;
    if (j <= i) return;

    __shared__ int hist[4][NAA * NAA];
    __shared__ float ra[NAA], cb[NAA];
    __shared__ int s_tot;
    __shared__ float wsum[4];

    const int tid = threadIdx.x;
    const int wave = tid >> 6;

    int* hf = &hist[0][0];
    for (int k = tid; k < 4 * NAA * NAA; k += 256) hf[k] = 0;
    __syncthreads();

    if (use_pack) {
        const unsigned char* ci = cols + i * N_SEQS;
        const unsigned char* cj = cols + j * N_SEQS;
        const int n0 = tid * 8;  // 256 threads x 8 seqs = 2048
        uint2 A = *(const uint2*)(ci + n0);
        uint2 B = *(const uint2*)(cj + n0);
        unsigned long long av = ((unsigned long long)A.y << 32) | A.x;
        unsigned long long bv = ((unsigned long long)B.y << 32) | B.x;
#pragma unroll
        for (int k = 0; k < 8; ++k) {
            int a = (int)((av >> (8 * k)) & 0xFF);
            int b = (int)((bv >> (8 * k)) & 0xFF);
            if (a < NAA && b < NAA) atomicAdd(&hist[wave][a * NAA + b], 1);
        }
    } else {
        for (int n = tid; n < N_SEQS; n += 256) {
            int a = msa[n * SEQ_LEN + i];
            int b = msa[n * SEQ_LEN + j];
            if (a < NAA && b < NAA) atomicAdd(&hist[wave][a * NAA + b], 1);
        }
    }
    __syncthreads();

    // merge wave histograms into hist[0]
    for (int k = tid; k < NAA * NAA; k += 256)
        hist[0][k] += hist[1][k] + hist[2][k] + hist[3][k];
    __syncthreads();

    // marginals
    if (tid < NAA) {
        int s = 0;
#pragma unroll
        for (int b = 0; b < NAA; ++b) s += hist[0][tid * NAA + b];
        ra[tid] = (float)s;
    } else if (tid >= 32 && tid < 32 + NAA) {
        int c = tid - 32;
        int s = 0;
#pragma unroll
        for (int a = 0; a < NAA; ++a) s += hist[0][a * NAA + c];
        cb[c] = (float)s;
    }
    __syncthreads();

    if (tid == 0) {
        float t = 0.0f;
#pragma unroll
        for (int a = 0; a < NAA; ++a) t += ra[a];
        s_tot = (int)t;
    }
    __syncthreads();

    const float ts = fmaxf((float)s_tot, 1.0f);
    const float inv = 1.0f / ts;
    float part = 0.0f;
    for (int k = tid; k < NAA * NAA; k += 256) {
        int J = hist[0][k];
        if (J > 0) {
            float p = (float)J * inv;
            float pi = ra[k / NAA] * inv;
            float pj = cb[k % NAA] * inv;
            float denom = fmaxf(pi * pj, 1e-30f);
            part += p * log2f(p / denom + 1e-10f);
        }
    }
#pragma unroll
    for (int off = 32; off > 0; off >>= 1) part += __shfl_down(part, off, 64);
    if ((tid & 63) == 0) wsum[wave] = part;
    __syncthreads();

    if (tid == 0) {
        float m = wsum[0] + wsum[1] + wsum[2] + wsum[3];
        m = (s_tot > 0) ? m : 0.0f;
        mi[i * SEQ_LEN + j] = m;
        mi[j * SEQ_LEN + i] = m;
    }
}

// ---------------------------------------------------------------------------
extern "C" void kernel_launch(void* const* d_in, const int* in_sizes, int n_in,
                              void* d_out, int out_size, void* d_ws, size_t ws_size,
                              hipStream_t stream) {
    const int* msa = (const int*)d_in[0];
    const float* pc = (const float*)d_in[1];

    float* pssm = (float*)d_out;                    // 512*20
    float* cons = pssm + SEQ_LEN * NAA;             // 512
    float* mi = cons + SEQ_LEN;                     // 512*512

    // zero the full MI matrix (diag + region outside [:100,:100])
    hipMemsetAsync(mi, 0, (size_t)SEQ_LEN * SEQ_LEN * sizeof(float), stream);

    unsigned char* cols = (unsigned char*)d_ws;
    const int use_pack = (ws_size >= (size_t)(MPOS * N_SEQS)) ? 1 : 0;
    if (use_pack) {
        pack_cols_kernel<<<MPOS, 256, 0, stream>>>(msa, cols);
    }

    pssm_cons_kernel<<<SEQ_LEN, 256, 0, stream>>>(msa, pc, pssm, cons);

    dim3 grid(MPOS, MPOS);
    mi_kernel<<<grid, 256, 0, stream>>>(msa, cols, use_pack, mi);
}

// Round 2
// 24.394 us; speedup vs baseline: 1.3930x; 1.3930x over previous
//
#include <hip/hip_runtime.h>

#define N_SEQS 2048
#define SEQ_LEN 512
#define NAA 20
#define MPOS 100
#define NPAIRS (MPOS * (MPOS - 1) / 2)  // 4950

// ---------------------------------------------------------------------------
// Fused per-position kernel: one block per position i.
//  - zeroes MI row i (covers diag + everything outside [:100,:100])
//  - packs column i into uint8 cols[i][2048] (i < 100) for the MI kernel
//  - computes pssm[i][:] and conservation[i]
// ---------------------------------------------------------------------------
__global__ __launch_bounds__(256) void pos_kernel(const int* __restrict__ msa,
                                                  const float* __restrict__ pc,
                                                  unsigned char* __restrict__ cols,
                                                  float* __restrict__ pssm,
                                                  float* __restrict__ cons,
                                                  float* __restrict__ mi) {
    __shared__ int hist[4][NAA];
    const int i = blockIdx.x;
    const int tid = threadIdx.x;
    const int wave = tid >> 6;

    // zero MI row i (512 floats = 128 float4)
    float4* row = (float4*)(mi + (size_t)i * SEQ_LEN);
    if (tid < SEQ_LEN / 4) row[tid] = make_float4(0.f, 0.f, 0.f, 0.f);

    if (tid < 4 * NAA) ((int*)hist)[tid] = 0;
    __syncthreads();

    int vals[8];
#pragma unroll
    for (int k = 0; k < 8; ++k) {
        vals[k] = msa[(tid + 256 * k) * SEQ_LEN + i];
    }
    if (i < MPOS) {
#pragma unroll
        for (int k = 0; k < 8; ++k)
            cols[i * N_SEQS + tid + 256 * k] = (unsigned char)vals[k];
    }
#pragma unroll
    for (int k = 0; k < 8; ++k) {
        if (vals[k] < NAA) atomicAdd(&hist[wave][vals[k]], 1);
    }
    __syncthreads();

    if (tid < NAA) {
        int c = hist[0][tid] + hist[1][tid] + hist[2][tid] + hist[3][tid];
        hist[0][tid] = c;
        float pcnt = 0.01f * pc[0];
        float freq = ((float)c + pcnt) / (2048.0f + pcnt * 20.0f);
        pssm[i * NAA + tid] = logf(freq * 20.0f + 1e-10f);
    }
    __syncthreads();
    if (tid == 0) {
        int t = 0;
#pragma unroll
        for (int a = 0; a < NAA; ++a) t += hist[0][a];
        float tot = (float)t;
        float ts = fmaxf(tot, 1.0f);
        float e = 0.0f;
#pragma unroll
        for (int a = 0; a < NAA; ++a) {
            float f = (float)hist[0][a] / ts;
            e -= f * log2f(f + 1e-10f);
        }
        cons[i] = (tot > 0.0f) ? (1.0f - e / 4.321928094887363f) : 0.0f;
    }
}

// ---------------------------------------------------------------------------
// MI: one block per (i<j) pair, triangular 1D grid of 4950 blocks.
// ---------------------------------------------------------------------------
__global__ __launch_bounds__(256) void mi_kernel(const unsigned char* __restrict__ cols,
                                                 float* __restrict__ mi) {
    const int t = blockIdx.x;
    // decode i: largest i with f(i) = i*(199-i)/2 <= t
    int i = (int)((199.0f - sqrtf(199.0f * 199.0f - 8.0f * (float)t)) * 0.5f);
    if (i < 0) i = 0;
    while ((i + 1) * (198 - i) / 2 <= t) ++i;
    while (i * (199 - i) / 2 > t) --i;
    const int j = i + 1 + (t - i * (199 - i) / 2);

    __shared__ int hist[4][NAA * NAA];
    __shared__ float ra[NAA], cb[NAA];
    __shared__ int s_tot;
    __shared__ float wsum[4];

    const int tid = threadIdx.x;
    const int wave = tid >> 6;

    int* hf = &hist[0][0];
    for (int k = tid; k < 4 * NAA * NAA; k += 256) hf[k] = 0;
    __syncthreads();

    {
        const unsigned char* ci = cols + i * N_SEQS;
        const unsigned char* cj = cols + j * N_SEQS;
        const int n0 = tid * 8;  // 256 threads x 8 seqs = 2048
        uint2 A = *(const uint2*)(ci + n0);
        uint2 B = *(const uint2*)(cj + n0);
        unsigned long long av = ((unsigned long long)A.y << 32) | A.x;
        unsigned long long bv = ((unsigned long long)B.y << 32) | B.x;
#pragma unroll
        for (int k = 0; k < 8; ++k) {
            int a = (int)((av >> (8 * k)) & 0xFF);
            int b = (int)((bv >> (8 * k)) & 0xFF);
            if (a < NAA && b < NAA) atomicAdd(&hist[wave][a * NAA + b], 1);
        }
    }
    __syncthreads();

    for (int k = tid; k < NAA * NAA; k += 256)
        hist[0][k] += hist[1][k] + hist[2][k] + hist[3][k];
    __syncthreads();

    if (tid < NAA) {
        int s = 0;
#pragma unroll
        for (int b = 0; b < NAA; ++b) s += hist[0][tid * NAA + b];
        ra[tid] = (float)s;
    } else if (tid >= 32 && tid < 32 + NAA) {
        int c = tid - 32;
        int s = 0;
#pragma unroll
        for (int a = 0; a < NAA; ++a) s += hist[0][a * NAA + c];
        cb[c] = (float)s;
    }
    __syncthreads();

    if (tid == 0) {
        float tt = 0.0f;
#pragma unroll
        for (int a = 0; a < NAA; ++a) tt += ra[a];
        s_tot = (int)tt;
    }
    __syncthreads();

    const float ts = fmaxf((float)s_tot, 1.0f);
    const float inv = 1.0f / ts;
    float part = 0.0f;
    for (int k = tid; k < NAA * NAA; k += 256) {
        int J = hist[0][k];
        if (J > 0) {
            float p = (float)J * inv;
            float pi = ra[k / NAA] * inv;
            float pj = cb[k % NAA] * inv;
            float denom = fmaxf(pi * pj, 1e-30f);
            part += p * log2f(p / denom + 1e-10f);
        }
    }
#pragma unroll
    for (int off = 32; off > 0; off >>= 1) part += __shfl_down(part, off, 64);
    if ((tid & 63) == 0) wsum[wave] = part;
    __syncthreads();

    if (tid == 0) {
        float m = wsum[0] + wsum[1] + wsum[2] + wsum[3];
        m = (s_tot > 0) ? m : 0.0f;
        mi[i * SEQ_LEN + j] = m;
        mi[j * SEQ_LEN + i] = m;
    }
}

// ---------------------------------------------------------------------------
extern "C" void kernel_launch(void* const* d_in, const int* in_sizes, int n_in,
                              void* d_out, int out_size, void* d_ws, size_t ws_size,
                              hipStream_t stream) {
    const int* msa = (const int*)d_in[0];
    const float* pc = (const float*)d_in[1];

    float* pssm = (float*)d_out;         // 512*20
    float* cons = pssm + SEQ_LEN * NAA;  // 512
    float* mi = cons + SEQ_LEN;          // 512*512

    unsigned char* cols = (unsigned char*)d_ws;  // 100*2048 bytes

    pos_kernel<<<SEQ_LEN, 256, 0, stream>>>(msa, pc, cols, pssm, cons, mi);
    mi_kernel<<<NPAIRS, 256, 0, stream>>>(cols, mi);
}

// Round 3
// 20.850 us; speedup vs baseline: 1.6298x; 1.1700x over previous
//
#include <hip/hip_runtime.h>

#define N_SEQS 2048
#define SEQ_LEN 512
#define NAA 20
#define NS 21                      // states including gap (pad bin)
#define MPOS 100
#define NPAIRS 4950                // 100*99/2
#define WPB 4                      // pairs (waves) per block
#define MI_BLOCKS ((NPAIRS + WPB - 1) / WPB)  // 1238

// ---------------------------------------------------------------------------
// Fused per-position kernel: block i zeroes MI row i, packs column i (i<100),
// computes pssm[i][:] and conservation[i]. 21-bin padded histogram -> no
// bounds check on the atomic update.
// ---------------------------------------------------------------------------
__global__ __launch_bounds__(256) void pos_kernel(const int* __restrict__ msa,
                                                  const float* __restrict__ pc,
                                                  unsigned char* __restrict__ cols,
                                                  float* __restrict__ pssm,
                                                  float* __restrict__ cons,
                                                  float* __restrict__ mi) {
    __shared__ int hist[4][NS];
    __shared__ int cnt_s[NAA];
    const int i = blockIdx.x;
    const int tid = threadIdx.x;
    const int w = tid >> 6;

    // zero MI row i (covers diagonal + everything outside [:100,:100])
    float4* row = (float4*)(mi + (size_t)i * SEQ_LEN);
    if (tid < SEQ_LEN / 4) row[tid] = make_float4(0.f, 0.f, 0.f, 0.f);

    if (tid < 4 * NS) ((int*)hist)[tid] = 0;
    __syncthreads();

    int vals[8];
#pragma unroll
    for (int k = 0; k < 8; ++k) vals[k] = msa[(tid + 256 * k) * SEQ_LEN + i];
    if (i < MPOS) {
#pragma unroll
        for (int k = 0; k < 8; ++k)
            cols[i * N_SEQS + tid + 256 * k] = (unsigned char)vals[k];
    }
#pragma unroll
    for (int k = 0; k < 8; ++k) atomicAdd(&hist[w][vals[k]], 1);
    __syncthreads();

    if (tid < NAA) {
        int c = hist[0][tid] + hist[1][tid] + hist[2][tid] + hist[3][tid];
        cnt_s[tid] = c;
        float pcnt = 0.01f * pc[0];
        float freq = ((float)c + pcnt) / (2048.0f + pcnt * 20.0f);
        pssm[i * NAA + tid] = __logf(freq * 20.0f + 1e-10f);
    }
    __syncthreads();

    // conservation: wave 0, lanes 0..19 hold counts, shuffle-reduce
    if (tid < 64) {
        float fc = (tid < NAA) ? (float)cnt_s[tid] : 0.f;
        float tot = fc;
#pragma unroll
        for (int off = 32; off; off >>= 1) tot += __shfl_xor(tot, off, 64);
        float ts = fmaxf(tot, 1.f);
        float f = __fdividef(fc, ts);
        float term = (tid < NAA) ? -f * __log2f(f + 1e-10f) : 0.f;
#pragma unroll
        for (int off = 32; off; off >>= 1) term += __shfl_xor(term, off, 64);
        if (tid == 0)
            cons[i] = (tot > 0.f) ? (1.f - term * 0.2313782131597592f) : 0.f; // 1/log2(20)
    }
}

// ---------------------------------------------------------------------------
// MI: ONE PAIR PER WAVE, 4 waves per block. Wave-private 21x21 histogram,
// unconditional atomics, wave-local marginals + log2 pass + shuffle reduce.
// ---------------------------------------------------------------------------
__global__ __launch_bounds__(256) void mi_kernel(const unsigned char* __restrict__ cols,
                                                 float* __restrict__ mi) {
    __shared__ int hist[WPB][NS * NS];       // 4*441*4 = 7056 B
    __shared__ float ra_s[WPB][NAA];
    __shared__ float cb_s[WPB][NAA];

    const int tid = threadIdx.x;
    const int w = tid >> 6;
    const int lane = tid & 63;

    int t = blockIdx.x * WPB + w;
    const bool active = (t < NPAIRS);
    if (!active) t = 0;

    // decode (i<j) from triangular index t
    int i = (int)((199.0f - sqrtf(39601.0f - 8.0f * (float)t)) * 0.5f);
    if (i < 0) i = 0;
    while ((i + 1) * (198 - i) / 2 <= t) ++i;
    while (i * (199 - i) / 2 > t) --i;
    const int j = i + 1 + (t - i * (199 - i) / 2);

    // zero own histogram
#pragma unroll
    for (int u = 0; u < 7; ++u) {
        int k = lane + 64 * u;
        if (k < NS * NS) hist[w][k] = 0;
    }
    __syncthreads();

    if (active) {
        const uint4* ci = (const uint4*)(cols + i * N_SEQS + lane * 32);
        const uint4* cj = (const uint4*)(cols + j * N_SEQS + lane * 32);
        uint4 A0 = ci[0], A1 = ci[1];
        uint4 B0 = cj[0], B1 = cj[1];
        unsigned int aw[8] = {A0.x, A0.y, A0.z, A0.w, A1.x, A1.y, A1.z, A1.w};
        unsigned int bw[8] = {B0.x, B0.y, B0.z, B0.w, B1.x, B1.y, B1.z, B1.w};
#pragma unroll
        for (int q = 0; q < 8; ++q) {
            unsigned int av = aw[q], bv = bw[q];
#pragma unroll
            for (int byte = 0; byte < 4; ++byte) {
                int a = (av >> (8 * byte)) & 0xFF;
                int b = (bv >> (8 * byte)) & 0xFF;
                atomicAdd(&hist[w][a * NS + b], 1);   // padded: no bounds check
            }
        }
    }
    __syncthreads();

    // wave-local marginals over the 20x20 valid sub-block
    if (lane < NAA) {
        int s = 0;
#pragma unroll
        for (int b = 0; b < NAA; ++b) s += hist[w][lane * NS + b];
        ra_s[w][lane] = (float)s;
    } else if (lane >= 32 && lane < 32 + NAA) {
        int c = lane - 32, s = 0;
#pragma unroll
        for (int a = 0; a < NAA; ++a) s += hist[w][a * NS + c];
        cb_s[w][c] = (float)s;
    }
    __syncthreads();

    float tot = 0.f;
#pragma unroll
    for (int a = 0; a < NAA; ++a) tot += ra_s[w][a];
    const float ts = fmaxf(tot, 1.f);
    const float inv = __fdividef(1.f, ts);

    float part = 0.f;
#pragma unroll
    for (int u = 0; u < 7; ++u) {
        int k = lane + 64 * u;
        if (k < NAA * NAA) {
            int row = k / NAA;
            int col = k - row * NAA;
            int J = hist[w][row * NS + col];
            if (J > 0) {
                float p = (float)J * inv;
                float pi = ra_s[w][row] * inv;
                float pj = cb_s[w][col] * inv;
                float denom = fmaxf(pi * pj, 1e-30f);
                part += p * __log2f(__fdividef(p, denom) + 1e-10f);
            }
        }
    }
#pragma unroll
    for (int off = 32; off; off >>= 1) part += __shfl_down(part, off, 64);

    if (active && lane == 0) {
        float m = (tot > 0.f) ? part : 0.f;
        mi[i * SEQ_LEN + j] = m;
        mi[j * SEQ_LEN + i] = m;
    }
}

// ---------------------------------------------------------------------------
extern "C" void kernel_launch(void* const* d_in, const int* in_sizes, int n_in,
                              void* d_out, int out_size, void* d_ws, size_t ws_size,
                              hipStream_t stream) {
    const int* msa = (const int*)d_in[0];
    const float* pc = (const float*)d_in[1];

    float* pssm = (float*)d_out;         // 512*20
    float* cons = pssm + SEQ_LEN * NAA;  // 512
    float* mi = cons + SEQ_LEN;          // 512*512

    unsigned char* cols = (unsigned char*)d_ws;  // 100*2048 bytes

    pos_kernel<<<SEQ_LEN, 256, 0, stream>>>(msa, pc, cols, pssm, cons, mi);
    mi_kernel<<<MI_BLOCKS, 256, 0, stream>>>(cols, mi);
}